// Round 1
// baseline (203.335 us; speedup 1.0000x reference)
//
#include <hip/hip_runtime.h>

#define N_B    64
#define T_S    32
#define DIM    12288            // 3*64*64
#define ROWS   2048             // N_B*T_S
#define NCOL   12               // used GEMM columns (3 obj * 4)
#define KSPL   32               // split-K factor
#define KSEG   (DIM / KSPL)     // 384
#define BK     128              // k-chunk staged in LDS
#define NCHUNK (KSEG / BK)      // 3
#define RPBK   64               // rows per block (one per lane)

// ---------------- Kernel 0: repack W into per-wave column-planes -----------
// Wp[w][k][cc] = W[k][colmap(w*3+cc)], w=0..3, cc=0..2.
// Makes the GEMM's W stream 12 *consecutive* floats per 4-k step -> the
// compiler can fetch it with wide uniform (scalar) loads.
__global__ __launch_bounds__(256) void k_repack(const float* __restrict__ W,
                                                float* __restrict__ Wp) {
    const int idx = blockIdx.x * 256 + threadIdx.x;   // 0..147455
    const int w   = idx / (DIM * 3);
    const int rem = idx - w * (DIM * 3);
    const int k   = rem / 3;
    const int cc  = rem - k * 3;
    const int c   = w * 3 + cc;                       // logical col 0..11
    const int col = (c >> 2) * 8 + (c & 3);           // W column
    Wp[idx] = W[(size_t)k * 24 + col];
}

// ---------------- Kernel 1: row-per-lane split-K skinny GEMM ---------------
// Grid: 1024 blocks = 32 row-groups x 32 k-segments. Block = 4 waves.
// Lane owns one row; wave owns 3 output columns; x staged through swizzled
// LDS; W arrives as wave-uniform scalar loads. NO cross-lane reduction.
__global__ __launch_bounds__(256) void k_gemm2(const float* __restrict__ x,
                                               const float* __restrict__ Wp,
                                               float* __restrict__ part) {
    __shared__ float4 xt[RPBK * (BK / 4)];        // 64 rows x 32 float4 = 32 KB
    const int tid  = threadIdx.x;
    const int lane = tid & 63;
    const int rb   = blockIdx.x >> 5;             // row group 0..31
    const int sg   = blockIdx.x & 31;             // k segment 0..31
    const int r0   = rb * RPBK;
    const int k00  = sg * KSEG;
    // force wave id into an SGPR so all W addresses are provably uniform
    const int wv   = __builtin_amdgcn_readfirstlane(tid >> 6);

    const float* wbase = Wp + (size_t)wv * (DIM * 3) + (size_t)k00 * 3;
    const float* xb    = x + (size_t)r0 * DIM + k00;

    // prefetch chunk 0 into registers (pure HBM-miss stream)
    float4 st[8];
#pragma unroll
    for (int i = 0; i < 8; ++i) {
        const int f = tid + 256 * i;              // flat float4 id, 0..2047
        st[i] = *(const float4*)(xb + (size_t)(f >> 5) * DIM + (f & 31) * 4);
    }

    float acc0 = 0.f, acc1 = 0.f, acc2 = 0.f;

    for (int ch = 0; ch < NCHUNK; ++ch) {
        __syncthreads();                          // LDS free (prev chunk read)
        // regs -> LDS, XOR-swizzled at float4 granularity (2-way max = free)
#pragma unroll
        for (int i = 0; i < 8; ++i) {
            const int f   = tid + 256 * i;
            const int row = f >> 5;
            const int c4  = (f & 31) ^ (row & 7);
            xt[row * 32 + c4] = st[i];
        }
        __syncthreads();
        // issue next chunk's global loads NOW -> HBM latency hides under FMA
        if (ch + 1 < NCHUNK) {
#pragma unroll
            for (int i = 0; i < 8; ++i) {
                const int f = tid + 256 * i;
                st[i] = *(const float4*)(xb + (size_t)(f >> 5) * DIM +
                                         (ch + 1) * BK + (f & 31) * 4);
            }
        }
        const float* wc = wbase + ch * (BK * 3);
#pragma unroll
        for (int g = 0; g < 8; ++g) {
            // 48 consecutive wave-uniform floats: 16 k x 3 cols -> s_load wide
            const float* wg = wc + g * 48;
            float ws[48];
#pragma unroll
            for (int q = 0; q < 48; ++q) ws[q] = wg[q];
#pragma unroll
            for (int jj = 0; jj < 4; ++jj) {
                const int j = g * 4 + jj;
                const float4 xv = xt[lane * 32 + (j ^ (lane & 7))];
                acc0 += xv.x * ws[jj*12 + 0] + xv.y * ws[jj*12 + 3] +
                        xv.z * ws[jj*12 + 6] + xv.w * ws[jj*12 + 9];
                acc1 += xv.x * ws[jj*12 + 1] + xv.y * ws[jj*12 + 4] +
                        xv.z * ws[jj*12 + 7] + xv.w * ws[jj*12 + 10];
                acc2 += xv.x * ws[jj*12 + 2] + xv.y * ws[jj*12 + 5] +
                        xv.z * ws[jj*12 + 8] + xv.w * ws[jj*12 + 11];
            }
        }
    }

    // part[sg][row][c], c = wv*3 + cc
    float* p = part + (size_t)sg * (ROWS * NCOL) +
               (size_t)(r0 + lane) * NCOL + wv * 3;
    p[0] = acc0; p[1] = acc1; p[2] = acc2;
}

// ---------------- Kernel 2: reduce split-K + constrain + match + fix -------
__global__ __launch_bounds__(64) void k_post(const float* __restrict__ part,
                                             const float* __restrict__ b_enc,
                                             float* __restrict__ out) {
    __shared__ float z[T_S * NCOL];
    __shared__ float zm[T_S * NCOL];
    __shared__ float zf[T_S * NCOL];
    __shared__ int   perm[T_S];
    const int b   = blockIdx.x;
    const int tid = threadIdx.x;

    // fused split-K reduce + bias + sigmoid constrain (was k_reduce)
#pragma unroll
    for (int ii = 0; ii < 6; ++ii) {
        const int i = tid + 64 * ii;              // t*12 + c for this batch row
        float s = 0.f;
#pragma unroll
        for (int sgi = 0; sgi < KSPL; ++sgi)
            s += part[(size_t)sgi * (ROWS * NCOL) + b * 384 + i];
        const int c  = i % 12;
        const int o  = c >> 2;
        const int cp = c & 3;
        s += b_enc[o * 8 + cp];
        const float sgm = 1.f / (1.f + expf(-s));
        float v;
        if (cp == 0)      v = sgm * 0.7f + 0.1f;
        else if (cp == 1) v = sgm * 0.5f + 0.75f;
        else              v = (2.f * sgm - 1.f) * 0.9f;
        z[i] = v;
    }
    __syncthreads();

    if (tid == 0) {
        float px0 = z[2],  py0 = z[3];
        float px1 = z[6],  py1 = z[7];
        float px2 = z[10], py2 = z[11];
        for (int t = 1; t < T_S; ++t) {
            const int base = t * 12;
            const float cx0 = z[base + 2],  cy0 = z[base + 3];
            const float cx1 = z[base + 6],  cy1 = z[base + 7];
            const float cx2 = z[base + 10], cy2 = z[base + 11];

            float dx, dy;
            dx = px0 - cx0; dy = py0 - cy0; const float e00 = dx * dx + dy * dy;
            dx = px0 - cx1; dy = py0 - cy1; const float e01 = dx * dx + dy * dy;
            dx = px0 - cx2; dy = py0 - cy2; const float e02 = dx * dx + dy * dy;
            dx = px1 - cx0; dy = py1 - cy0; const float e10 = dx * dx + dy * dy;
            dx = px1 - cx1; dy = py1 - cy1; const float e11 = dx * dx + dy * dy;
            dx = px1 - cx2; dy = py1 - cy2; const float e12 = dx * dx + dy * dy;
            dx = px2 - cx0; dy = py2 - cy0; const float e20 = dx * dx + dy * dy;
            dx = px2 - cx1; dy = py2 - cy1; const float e21 = dx * dx + dy * dy;
            dx = px2 - cx2; dy = py2 - cy2; const float e22 = dx * dx + dy * dy;

            auto amin3 = [](float a0, float a1, float a2) {
                int j = 0; float e = a0;
                if (a1 < e) { e = a1; j = 1; }
                if (a2 < e) { j = 2; }
                return j;
            };
            int i0 = amin3(e00, e01, e02);
            int i1 = amin3(e10, e11, e12);
            int i2 = amin3(e20, e21, e22);
            const bool ok = (i1 != i0) && (i2 != i1) && (i0 != i2);
            if (!ok) {
                float u0 = 0.f, u1 = 0.f, u2 = 0.f;
                i0 = amin3(e00, e01, e02);
                if (i0 == 0) u0 = 1.f; else if (i0 == 1) u1 = 1.f; else u2 = 1.f;
                i1 = amin3(e10 + u0 * 1e12f, e11 + u1 * 1e12f, e12 + u2 * 1e12f);
                if (i1 == 0) u0 = 1.f; else if (i1 == 1) u1 = 1.f; else u2 = 1.f;
                i2 = amin3(e20 + u0 * 1e12f, e21 + u1 * 1e12f, e22 + u2 * 1e12f);
            }
            perm[t] = i0 * 9 + i1 * 3 + i2;
            px0 = (i0 == 0) ? cx0 : (i0 == 1) ? cx1 : cx2;
            py0 = (i0 == 0) ? cy0 : (i0 == 1) ? cy1 : cy2;
            px1 = (i1 == 0) ? cx0 : (i1 == 1) ? cx1 : cx2;
            py1 = (i1 == 0) ? cy0 : (i1 == 1) ? cy1 : cy2;
            px2 = (i2 == 0) ? cx0 : (i2 == 1) ? cx1 : cx2;
            py2 = (i2 == 0) ? cy0 : (i2 == 1) ? cy1 : cy2;
        }
    }
    __syncthreads();

#pragma unroll
    for (int ii = 0; ii < 6; ++ii) {
        const int i  = tid + 64 * ii;
        const int t  = i / 12;
        const int j  = i - t * 12;
        const int k  = j >> 2;
        const int ch = j & 3;
        int p = k;
        if (t > 0) {
            const int code = perm[t];
            p = (k == 0) ? code / 9 : (k == 1) ? (code % 9) / 3 : code % 3;
        }
        zm[i] = z[t * 12 + p * 4 + ch];
    }
    __syncthreads();

#pragma unroll
    for (int ii = 0; ii < 6; ++ii) {
        const int i  = tid + 64 * ii;
        const int t  = i / 12;
        const int j  = i - t * 12;
        const int o  = j >> 2;
        const int cc = j & 1;
        const int mb = o * 4 + cc;
        const float pd = (t >= 1)  ? fabsf(zm[t * 12 + mb] - zm[(t - 1) * 12 + mb]) : 0.f;
        const float ad = (t <= 30) ? fabsf(zm[(t + 1) * 12 + mb] - zm[t * 12 + mb]) : 0.f;
        const bool  m  = (pd > 0.095f) && (ad > 0.095f);
        const float sm = (t >= 1 && t <= 30)
                             ? (zm[(t - 1) * 12 + j] + zm[(t + 1) * 12 + j]) * 0.5f
                             : 0.f;
        zf[i] = m ? sm : zm[t * 12 + j];
    }
    __syncthreads();

    for (int i = tid; i < 31 * 12; i += 64) {
        const int t  = i / 12;
        const int j  = i - t * 12;
        const int o  = j >> 2;
        const int c2 = j & 3;
        const int pb = o * 4 + 2 + (c2 & 1);
        float v;
        if (c2 < 2) v = zf[(t + 1) * 12 + pb] + 1.f;
        else        v = (zf[(t + 1) * 12 + pb] - zf[t * 12 + pb]) * 10.f;
        out[b * 372 + i] = v;
    }
}

extern "C" void kernel_launch(void* const* d_in, const int* in_sizes, int n_in,
                              void* d_out, int out_size, void* d_ws, size_t ws_size,
                              hipStream_t stream) {
    (void)in_sizes; (void)n_in; (void)out_size; (void)ws_size;
    const float* x     = (const float*)d_in[0];
    const float* W_enc = (const float*)d_in[1];
    const float* b_enc = (const float*)d_in[2];
    float* out  = (float*)d_out;

    float* part = (float*)d_ws;                     // 32*24576 floats = 3.1 MB
    float* Wp   = part + (size_t)KSPL * ROWS * NCOL; // 4*12288*3 floats

    k_repack<<<(4 * DIM * 3) / 256, 256, 0, stream>>>(W_enc, Wp);
    k_gemm2 <<<(ROWS / RPBK) * KSPL, 256, 0, stream>>>(x, Wp, part);
    k_post  <<<N_B, 64, 0, stream>>>(part, b_enc, out);
}

// Round 2
// 198.846 us; speedup vs baseline: 1.0226x; 1.0226x over previous
//
#include <hip/hip_runtime.h>

#define N_B    64
#define T_S    32
#define DIM    12288            // 3*64*64
#define ROWS   2048             // N_B*T_S
#define NCOL   12               // used GEMM columns (3 obj * 4)
#define KSPL   32               // split-K factor
#define KSEG   (DIM / KSPL)     // 384
#define BK     128              // k-chunk staged in LDS
#define NCHUNK (KSEG / BK)      // 3
#define RPBK   64               // rows per block (one per lane)
#define LDP    33               // padded LDS stride in float4 (33*16B = 528B)

// ---------------- Kernel 0: repack W into per-wave column-planes -----------
// Wp[w][k][cc] = W[k][colmap(w*3+cc)], w=0..3, cc=0..2.
// GEMM's W stream is then 12 consecutive floats per 4-k step.
__global__ __launch_bounds__(256) void k_repack(const float* __restrict__ W,
                                                float* __restrict__ Wp) {
    const int idx = blockIdx.x * 256 + threadIdx.x;   // 0..147455
    const int w   = idx / (DIM * 3);
    const int rem = idx - w * (DIM * 3);
    const int k   = rem / 3;
    const int cc  = rem - k * 3;
    const int c   = w * 3 + cc;                       // logical col 0..11
    const int col = (c >> 2) * 8 + (c & 3);           // W column
    Wp[idx] = W[(size_t)k * 24 + col];
}

// ---------------- Kernel 1: row-per-lane split-K skinny GEMM ---------------
// Grid: 1024 blocks = 32 row-groups x 32 k-segments. Block = 4 waves.
// Lane owns one row; wave owns 3 output columns. x staged through PADDED
// LDS (conflict-free both sides). W consumed as immediate float4 loads
// (12 floats live at a time -> no spill, no scalar-load wall).
__global__ __launch_bounds__(256, 4) void k_gemm2(const float* __restrict__ x,
                                                  const float* __restrict__ Wp,
                                                  float* __restrict__ part) {
    __shared__ float4 xt[RPBK * LDP];             // 64 x 33 float4 = 33792 B
    const int tid  = threadIdx.x;
    const int lane = tid & 63;
    const int rb   = blockIdx.x >> 5;             // row group 0..31
    const int sg   = blockIdx.x & 31;             // k segment 0..31
    const int r0   = rb * RPBK;
    const int k00  = sg * KSEG;
    const int wv   = __builtin_amdgcn_readfirstlane(tid >> 6);  // uniform wave id

    const float* wbase = Wp + (size_t)wv * (DIM * 3) + (size_t)k00 * 3;
    const float* xb    = x + (size_t)r0 * DIM + k00;

    // prefetch chunk 0 into registers (pure HBM-miss stream, coalesced)
    float4 st[8];
#pragma unroll
    for (int i = 0; i < 8; ++i) {
        const int f = tid + 256 * i;              // flat float4 id, 0..2047
        st[i] = *(const float4*)(xb + (size_t)(f >> 5) * DIM + (f & 31) * 4);
    }

    float acc0 = 0.f, acc1 = 0.f, acc2 = 0.f;

    for (int ch = 0; ch < NCHUNK; ++ch) {
        __syncthreads();                          // LDS free (prev chunk read)
        // regs -> LDS: 32 consecutive lanes write 32 consecutive float4s
        // within one padded row -> conflict-free, no swizzle needed
#pragma unroll
        for (int i = 0; i < 8; ++i) {
            const int f = tid + 256 * i;
            xt[(f >> 5) * LDP + (f & 31)] = st[i];
        }
        __syncthreads();
        // issue next chunk's global loads NOW -> HBM latency hides under FMA
        if (ch + 1 < NCHUNK) {
#pragma unroll
            for (int i = 0; i < 8; ++i) {
                const int f = tid + 256 * i;
                st[i] = *(const float4*)(xb + (size_t)(f >> 5) * DIM +
                                         (ch + 1) * BK + (f & 31) * 4);
            }
        }
        const float* wc = wbase + ch * (BK * 3);
        // 4 k per step: 12 consecutive W floats (3 float4), consumed at once.
#pragma unroll 4
        for (int j = 0; j < 32; ++j) {
            const float4 w0 = *(const float4*)(wc + j * 12 + 0);
            const float4 w1 = *(const float4*)(wc + j * 12 + 4);
            const float4 w2 = *(const float4*)(wc + j * 12 + 8);
            // read: bank = (4*lane + 4*j) % 32 -> each 8-lane group covers
            // all 32 banks exactly once -> conflict-free ds_read_b128
            const float4 xv = xt[lane * LDP + j];
            acc0 += xv.x * w0.x + xv.y * w0.w + xv.z * w1.z + xv.w * w2.y;
            acc1 += xv.x * w0.y + xv.y * w1.x + xv.z * w1.w + xv.w * w2.z;
            acc2 += xv.x * w0.z + xv.y * w1.y + xv.z * w2.x + xv.w * w2.w;
        }
    }

    // stage outputs through LDS -> fully coalesced part store
    __syncthreads();
    float* red = (float*)xt;                      // 768 floats needed
    red[lane * NCOL + wv * 3 + 0] = acc0;
    red[lane * NCOL + wv * 3 + 1] = acc1;
    red[lane * NCOL + wv * 3 + 2] = acc2;
    __syncthreads();
    float* p = part + (size_t)sg * (ROWS * NCOL) + (size_t)rb * (RPBK * NCOL);
    p[tid * 3 + 0] = red[tid * 3 + 0];
    p[tid * 3 + 1] = red[tid * 3 + 1];
    p[tid * 3 + 2] = red[tid * 3 + 2];
}

// ---------------- Kernel 2: reduce split-K + constrain + match + fix -------
__global__ __launch_bounds__(64) void k_post(const float* __restrict__ part,
                                             const float* __restrict__ b_enc,
                                             float* __restrict__ out) {
    __shared__ float z[T_S * NCOL];
    __shared__ float zm[T_S * NCOL];
    __shared__ float zf[T_S * NCOL];
    __shared__ int   perm[T_S];
    const int b   = blockIdx.x;
    const int tid = threadIdx.x;

    // fused split-K reduce + bias + sigmoid constrain
#pragma unroll
    for (int ii = 0; ii < 6; ++ii) {
        const int i = tid + 64 * ii;              // t*12 + c for this batch row
        float s = 0.f;
#pragma unroll
        for (int sgi = 0; sgi < KSPL; ++sgi)
            s += part[(size_t)sgi * (ROWS * NCOL) + b * 384 + i];
        const int c  = i % 12;
        const int o  = c >> 2;
        const int cp = c & 3;
        s += b_enc[o * 8 + cp];
        const float sgm = 1.f / (1.f + expf(-s));
        float v;
        if (cp == 0)      v = sgm * 0.7f + 0.1f;
        else if (cp == 1) v = sgm * 0.5f + 0.75f;
        else              v = (2.f * sgm - 1.f) * 0.9f;
        z[i] = v;
    }
    __syncthreads();

    if (tid == 0) {
        float px0 = z[2],  py0 = z[3];
        float px1 = z[6],  py1 = z[7];
        float px2 = z[10], py2 = z[11];
        for (int t = 1; t < T_S; ++t) {
            const int base = t * 12;
            const float cx0 = z[base + 2],  cy0 = z[base + 3];
            const float cx1 = z[base + 6],  cy1 = z[base + 7];
            const float cx2 = z[base + 10], cy2 = z[base + 11];

            float dx, dy;
            dx = px0 - cx0; dy = py0 - cy0; const float e00 = dx * dx + dy * dy;
            dx = px0 - cx1; dy = py0 - cy1; const float e01 = dx * dx + dy * dy;
            dx = px0 - cx2; dy = py0 - cy2; const float e02 = dx * dx + dy * dy;
            dx = px1 - cx0; dy = py1 - cy0; const float e10 = dx * dx + dy * dy;
            dx = px1 - cx1; dy = py1 - cy1; const float e11 = dx * dx + dy * dy;
            dx = px1 - cx2; dy = py1 - cy2; const float e12 = dx * dx + dy * dy;
            dx = px2 - cx0; dy = py2 - cy0; const float e20 = dx * dx + dy * dy;
            dx = px2 - cx1; dy = py2 - cy1; const float e21 = dx * dx + dy * dy;
            dx = px2 - cx2; dy = py2 - cy2; const float e22 = dx * dx + dy * dy;

            auto amin3 = [](float a0, float a1, float a2) {
                int j = 0; float e = a0;
                if (a1 < e) { e = a1; j = 1; }
                if (a2 < e) { j = 2; }
                return j;
            };
            int i0 = amin3(e00, e01, e02);
            int i1 = amin3(e10, e11, e12);
            int i2 = amin3(e20, e21, e22);
            const bool ok = (i1 != i0) && (i2 != i1) && (i0 != i2);
            if (!ok) {
                float u0 = 0.f, u1 = 0.f, u2 = 0.f;
                i0 = amin3(e00, e01, e02);
                if (i0 == 0) u0 = 1.f; else if (i0 == 1) u1 = 1.f; else u2 = 1.f;
                i1 = amin3(e10 + u0 * 1e12f, e11 + u1 * 1e12f, e12 + u2 * 1e12f);
                if (i1 == 0) u0 = 1.f; else if (i1 == 1) u1 = 1.f; else u2 = 1.f;
                i2 = amin3(e20 + u0 * 1e12f, e21 + u1 * 1e12f, e22 + u2 * 1e12f);
            }
            perm[t] = i0 * 9 + i1 * 3 + i2;
            px0 = (i0 == 0) ? cx0 : (i0 == 1) ? cx1 : cx2;
            py0 = (i0 == 0) ? cy0 : (i0 == 1) ? cy1 : cy2;
            px1 = (i1 == 0) ? cx0 : (i1 == 1) ? cx1 : cx2;
            py1 = (i1 == 0) ? cy0 : (i1 == 1) ? cy1 : cy2;
            px2 = (i2 == 0) ? cx0 : (i2 == 1) ? cx1 : cx2;
            py2 = (i2 == 0) ? cy0 : (i2 == 1) ? cy1 : cy2;
        }
    }
    __syncthreads();

#pragma unroll
    for (int ii = 0; ii < 6; ++ii) {
        const int i  = tid + 64 * ii;
        const int t  = i / 12;
        const int j  = i - t * 12;
        const int k  = j >> 2;
        const int ch = j & 3;
        int p = k;
        if (t > 0) {
            const int code = perm[t];
            p = (k == 0) ? code / 9 : (k == 1) ? (code % 9) / 3 : code % 3;
        }
        zm[i] = z[t * 12 + p * 4 + ch];
    }
    __syncthreads();

#pragma unroll
    for (int ii = 0; ii < 6; ++ii) {
        const int i  = tid + 64 * ii;
        const int t  = i / 12;
        const int j  = i - t * 12;
        const int o  = j >> 2;
        const int cc = j & 1;
        const int mb = o * 4 + cc;
        const float pd = (t >= 1)  ? fabsf(zm[t * 12 + mb] - zm[(t - 1) * 12 + mb]) : 0.f;
        const float ad = (t <= 30) ? fabsf(zm[(t + 1) * 12 + mb] - zm[t * 12 + mb]) : 0.f;
        const bool  m  = (pd > 0.095f) && (ad > 0.095f);
        const float sm = (t >= 1 && t <= 30)
                             ? (zm[(t - 1) * 12 + j] + zm[(t + 1) * 12 + j]) * 0.5f
                             : 0.f;
        zf[i] = m ? sm : zm[t * 12 + j];
    }
    __syncthreads();

    for (int i = tid; i < 31 * 12; i += 64) {
        const int t  = i / 12;
        const int j  = i - t * 12;
        const int o  = j >> 2;
        const int c2 = j & 3;
        const int pb = o * 4 + 2 + (c2 & 1);
        float v;
        if (c2 < 2) v = zf[(t + 1) * 12 + pb] + 1.f;
        else        v = (zf[(t + 1) * 12 + pb] - zf[t * 12 + pb]) * 10.f;
        out[b * 372 + i] = v;
    }
}

extern "C" void kernel_launch(void* const* d_in, const int* in_sizes, int n_in,
                              void* d_out, int out_size, void* d_ws, size_t ws_size,
                              hipStream_t stream) {
    (void)in_sizes; (void)n_in; (void)out_size; (void)ws_size;
    const float* x     = (const float*)d_in[0];
    const float* W_enc = (const float*)d_in[1];
    const float* b_enc = (const float*)d_in[2];
    float* out  = (float*)d_out;

    float* part = (float*)d_ws;                      // 32*24576 floats = 3.1 MB
    float* Wp   = part + (size_t)KSPL * ROWS * NCOL; // 4*12288*3 floats

    k_repack<<<(4 * DIM * 3) / 256, 256, 0, stream>>>(W_enc, Wp);
    k_gemm2 <<<(ROWS / RPBK) * KSPL, 256, 0, stream>>>(x, Wp, part);
    k_post  <<<N_B, 64, 0, stream>>>(part, b_enc, out);
}

// Round 4
// 177.395 us; speedup vs baseline: 1.1462x; 1.1209x over previous
//
#include <hip/hip_runtime.h>

#define N_B    64
#define T_S    32
#define DIM    12288            // 3*64*64
#define ROWS   2048             // N_B*T_S
#define NCOL   12               // used GEMM columns (3 obj * 4)
#define KSPL   64               // split-K factor
#define KSEG   (DIM / KSPL)     // 192
#define RPB    32               // rows per block (4 waves * 4 groups * 2 rows)
#define RPL    2                // rows per lane

// rotate-right within 16-lane DPP row, add into v (pure VALU, no DS pipe)
#define ROR16_ADD(v, n)                                                        \
    v += __int_as_float(__builtin_amdgcn_update_dpp(                           \
        0, __float_as_int(v), 0x120 | (n), 0xF, 0xF, true))

// ---------------- Kernel 1: DPP-reduced split-K skinny GEMM ----------------
// Grid: 4096 blocks = 64 row-groups x 64 k-segments. Block = 4 waves.
// Wave = 4 groups x 16 lanes: rows across groups, k split across 16 lanes.
// x: hoisted register miss-stream (never through LDS). W: 9 KB LDS, staged
// once, conflict-free b128 reads (2-way = free), 16 FMA/read. Reduction:
// 4 DPP rotate-adds (VALU) instead of 6 DS-swizzle butterfly steps.
// ONE barrier total.
__global__ __launch_bounds__(256, 5) void k_gemm3(const float* __restrict__ x,
                                                  const float* __restrict__ W,
                                                  float* __restrict__ part) {
    __shared__ float wt[NCOL * KSEG];        // [c][k], 9216 B
    const int tid  = threadIdx.x;
    const int w    = tid >> 6;
    const int lane = tid & 63;
    const int rg   = lane >> 4;              // group 0..3 (DPP row)
    const int kl   = lane & 15;              // k-lane 0..15
    const int rb   = blockIdx.x >> 6;        // row group 0..63
    const int sg   = blockIdx.x & 63;        // k segment 0..63
    const int r0   = rb * RPB;
    const int k00  = sg * KSEG;

    // ---- W loads FIRST (L2/L3-resident, returns fast; issuing them before
    // the x misses keeps the LDS stage off the HBM-latency vmcnt queue) ----
    float4 wv0 = make_float4(0.f, 0.f, 0.f, 0.f);
    float4 wv1 = wv0, wv2 = wv0;
    if (tid < KSEG) {                        // threads 0..191, one k each
        const float* wr = W + (size_t)(k00 + tid) * 24;
        wv0 = *(const float4*)(wr + 0);      // cols 0..3
        wv1 = *(const float4*)(wr + 8);      // cols 8..11
        wv2 = *(const float4*)(wr + 16);     // cols 16..19
    }

    // ---- hoist ALL x loads: pure coalesced HBM miss stream ----------------
    // f4 idx = kl + 16*jj -> each 16-lane group reads 256B contiguous.
    float4 xr[RPL][3];
#pragma unroll
    for (int r = 0; r < RPL; ++r) {
        const int row = r0 + w * 8 + rg * 2 + r;
        const float* xp = x + (size_t)row * DIM + k00 + kl * 4;
#pragma unroll
        for (int jj = 0; jj < 3; ++jj)
            xr[r][jj] = *(const float4*)(xp + 64 * jj);
    }

    // ---- stage W -> LDS (waits only W's vmcnt slots, not the x misses) ----
    if (tid < KSEG) {
        wt[0 * KSEG + tid] = wv0.x;  wt[1 * KSEG + tid] = wv0.y;
        wt[2 * KSEG + tid] = wv0.z;  wt[3 * KSEG + tid] = wv0.w;
        wt[4 * KSEG + tid] = wv1.x;  wt[5 * KSEG + tid] = wv1.y;
        wt[6 * KSEG + tid] = wv1.z;  wt[7 * KSEG + tid] = wv1.w;
        wt[8 * KSEG + tid] = wv2.x;  wt[9 * KSEG + tid] = wv2.y;
        wt[10 * KSEG + tid] = wv2.z; wt[11 * KSEG + tid] = wv2.w;
    }
    __syncthreads();                         // the ONLY barrier

    float acc[RPL][NCOL];
#pragma unroll
    for (int r = 0; r < RPL; ++r)
#pragma unroll
        for (int c = 0; c < NCOL; ++c) acc[r][c] = 0.f;

    // ---- compute: 36 ds_read_b128 (2-way bank alias = free), 16 FMA each --
#pragma unroll
    for (int jj = 0; jj < 3; ++jj) {
        const int kq = kl * 4 + 64 * jj;
#pragma unroll
        for (int c = 0; c < NCOL; ++c) {
            const float4 q = *(const float4*)(wt + c * KSEG + kq);
#pragma unroll
            for (int r = 0; r < RPL; ++r)
                acc[r][c] += xr[r][jj].x * q.x + xr[r][jj].y * q.y +
                             xr[r][jj].z * q.z + xr[r][jj].w * q.w;
        }
    }

    // ---- 16-lane DPP rotate-add reduction (VALU only, no DS) --------------
#pragma unroll
    for (int r = 0; r < RPL; ++r)
#pragma unroll
        for (int c = 0; c < NCOL; ++c) {
            float s = acc[r][c];
            ROR16_ADD(s, 1);
            ROR16_ADD(s, 2);
            ROR16_ADD(s, 4);
            ROR16_ADD(s, 8);
            acc[r][c] = s;                   // all 16 lanes hold full sum
        }

    // ---- store: lane kl<12 owns column c=kl (static-index cndmask chain) --
    if (kl < NCOL) {
#pragma unroll
        for (int r = 0; r < RPL; ++r) {
            float v = acc[r][0];
#pragma unroll
            for (int c = 1; c < NCOL; ++c)
                if (kl == c) v = acc[r][c];
            const int row = r0 + w * 8 + rg * 2 + r;
            part[(size_t)sg * (ROWS * NCOL) + (size_t)row * NCOL + kl] = v;
        }
    }
}

// ---------------- Kernel 2: reduce split-K + constrain + match + fix -------
__global__ __launch_bounds__(64) void k_post(const float* __restrict__ part,
                                             const float* __restrict__ b_enc,
                                             float* __restrict__ out) {
    __shared__ float z[T_S * NCOL];
    __shared__ float zm[T_S * NCOL];
    __shared__ float zf[T_S * NCOL];
    __shared__ int   perm[T_S];
    const int b   = blockIdx.x;
    const int tid = threadIdx.x;

    // fused split-K reduce + bias + sigmoid constrain
#pragma unroll
    for (int ii = 0; ii < 6; ++ii) {
        const int i = tid + 64 * ii;              // t*12 + c for this batch row
        float s = 0.f;
#pragma unroll 16
        for (int sgi = 0; sgi < KSPL; ++sgi)
            s += part[(size_t)sgi * (ROWS * NCOL) + b * 384 + i];
        const int c  = i % 12;
        const int o  = c >> 2;
        const int cp = c & 3;
        s += b_enc[o * 8 + cp];
        const float sgm = 1.f / (1.f + expf(-s));
        float v;
        if (cp == 0)      v = sgm * 0.7f + 0.1f;
        else if (cp == 1) v = sgm * 0.5f + 0.75f;
        else              v = (2.f * sgm - 1.f) * 0.9f;
        z[i] = v;
    }
    __syncthreads();

    if (tid == 0) {
        float px0 = z[2],  py0 = z[3];
        float px1 = z[6],  py1 = z[7];
        float px2 = z[10], py2 = z[11];
        for (int t = 1; t < T_S; ++t) {
            const int base = t * 12;
            const float cx0 = z[base + 2],  cy0 = z[base + 3];
            const float cx1 = z[base + 6],  cy1 = z[base + 7];
            const float cx2 = z[base + 10], cy2 = z[base + 11];

            float dx, dy;
            dx = px0 - cx0; dy = py0 - cy0; const float e00 = dx * dx + dy * dy;
            dx = px0 - cx1; dy = py0 - cy1; const float e01 = dx * dx + dy * dy;
            dx = px0 - cx2; dy = py0 - cy2; const float e02 = dx * dx + dy * dy;
            dx = px1 - cx0; dy = py1 - cy0; const float e10 = dx * dx + dy * dy;
            dx = px1 - cx1; dy = py1 - cy1; const float e11 = dx * dx + dy * dy;
            dx = px1 - cx2; dy = py1 - cy2; const float e12 = dx * dx + dy * dy;
            dx = px2 - cx0; dy = py2 - cy0; const float e20 = dx * dx + dy * dy;
            dx = px2 - cx1; dy = py2 - cy1; const float e21 = dx * dx + dy * dy;
            dx = px2 - cx2; dy = py2 - cy2; const float e22 = dx * dx + dy * dy;

            auto amin3 = [](float a0, float a1, float a2) {
                int j = 0; float e = a0;
                if (a1 < e) { e = a1; j = 1; }
                if (a2 < e) { j = 2; }
                return j;
            };
            int i0 = amin3(e00, e01, e02);
            int i1 = amin3(e10, e11, e12);
            int i2 = amin3(e20, e21, e22);
            const bool ok = (i1 != i0) && (i2 != i1) && (i0 != i2);
            if (!ok) {
                float u0 = 0.f, u1 = 0.f, u2 = 0.f;
                i0 = amin3(e00, e01, e02);
                if (i0 == 0) u0 = 1.f; else if (i0 == 1) u1 = 1.f; else u2 = 1.f;
                i1 = amin3(e10 + u0 * 1e12f, e11 + u1 * 1e12f, e12 + u2 * 1e12f);
                if (i1 == 0) u0 = 1.f; else if (i1 == 1) u1 = 1.f; else u2 = 1.f;
                i2 = amin3(e20 + u0 * 1e12f, e21 + u1 * 1e12f, e22 + u2 * 1e12f);
            }
            perm[t] = i0 * 9 + i1 * 3 + i2;
            px0 = (i0 == 0) ? cx0 : (i0 == 1) ? cx1 : cx2;
            py0 = (i0 == 0) ? cy0 : (i0 == 1) ? cy1 : cy2;
            px1 = (i1 == 0) ? cx0 : (i1 == 1) ? cx1 : cx2;
            py1 = (i1 == 0) ? cy0 : (i1 == 1) ? cy1 : cy2;
            px2 = (i2 == 0) ? cx0 : (i2 == 1) ? cx1 : cx2;
            py2 = (i2 == 0) ? cy0 : (i2 == 1) ? cy1 : cy2;
        }
    }
    __syncthreads();

#pragma unroll
    for (int ii = 0; ii < 6; ++ii) {
        const int i  = tid + 64 * ii;
        const int t  = i / 12;
        const int j  = i - t * 12;
        const int k  = j >> 2;
        const int ch = j & 3;
        int p = k;
        if (t > 0) {
            const int code = perm[t];
            p = (k == 0) ? code / 9 : (k == 1) ? (code % 9) / 3 : code % 3;
        }
        zm[i] = z[t * 12 + p * 4 + ch];
    }
    __syncthreads();

#pragma unroll
    for (int ii = 0; ii < 6; ++ii) {
        const int i  = tid + 64 * ii;
        const int t  = i / 12;
        const int j  = i - t * 12;
        const int o  = j >> 2;
        const int cc = j & 1;
        const int mb = o * 4 + cc;
        const float pd = (t >= 1)  ? fabsf(zm[t * 12 + mb] - zm[(t - 1) * 12 + mb]) : 0.f;
        const float ad = (t <= 30) ? fabsf(zm[(t + 1) * 12 + mb] - zm[t * 12 + mb]) : 0.f;
        const bool  m  = (pd > 0.095f) && (ad > 0.095f);
        const float sm = (t >= 1 && t <= 30)
                             ? (zm[(t - 1) * 12 + j] + zm[(t + 1) * 12 + j]) * 0.5f
                             : 0.f;
        zf[i] = m ? sm : zm[t * 12 + j];
    }
    __syncthreads();

    for (int i = tid; i < 31 * 12; i += 64) {
        const int t  = i / 12;
        const int j  = i - t * 12;
        const int o  = j >> 2;
        const int c2 = j & 3;
        const int pb = o * 4 + 2 + (c2 & 1);
        float v;
        if (c2 < 2) v = zf[(t + 1) * 12 + pb] + 1.f;
        else        v = (zf[(t + 1) * 12 + pb] - zf[t * 12 + pb]) * 10.f;
        out[b * 372 + i] = v;
    }
}

extern "C" void kernel_launch(void* const* d_in, const int* in_sizes, int n_in,
                              void* d_out, int out_size, void* d_ws, size_t ws_size,
                              hipStream_t stream) {
    (void)in_sizes; (void)n_in; (void)out_size; (void)ws_size;
    const float* x     = (const float*)d_in[0];
    const float* W_enc = (const float*)d_in[1];
    const float* b_enc = (const float*)d_in[2];
    float* out  = (float*)d_out;

    float* part = (float*)d_ws;               // 64*24576 floats = 6.3 MB

    k_gemm3<<<(ROWS / RPB) * KSPL, 256, 0, stream>>>(x, W_enc, part);
    k_post <<<N_B, 64, 0, stream>>>(part, b_enc, out);
}

// Round 5
// 171.585 us; speedup vs baseline: 1.1850x; 1.0339x over previous
//
#include <hip/hip_runtime.h>

#define N_B    64
#define T_S    32
#define DIM    12288            // 3*64*64
#define ROWS   2048             // N_B*T_S
#define NCOL   12               // used GEMM columns (3 obj * 4)
#define KSPL   64               // split-K factor
#define KSEG   (DIM / KSPL)     // 192
#define RPB    32               // rows per block (4 waves * 4 groups * 2 rows)
#define RPL    2                // rows per lane

typedef float f4 __attribute__((ext_vector_type(4)));

// rotate-right within 16-lane DPP row, add into v (pure VALU, no DS pipe)
#define ROR16_ADD(v, n)                                                        \
    v += __int_as_float(__builtin_amdgcn_update_dpp(                           \
        0, __float_as_int(v), 0x120 | (n), 0xF, 0xF, true))

// ---------------- Kernel 1: DPP-reduced split-K skinny GEMM ----------------
// Identical to round 4 EXCEPT: x is read with nontemporal loads (nt policy)
// so the 96 MB zero-reuse stream does NOT allocate in L2/L3 and therefore
// does not evict the harness-fill's dirty lines (which showed up as ~98 MB
// of writeback traffic charged to this kernel in round 2's counters).
__global__ __launch_bounds__(256, 5) void k_gemm3(const float* __restrict__ x,
                                                  const float* __restrict__ W,
                                                  float* __restrict__ part) {
    __shared__ float wt[NCOL * KSEG];        // [c][k], 9216 B
    const int tid  = threadIdx.x;
    const int w    = tid >> 6;
    const int lane = tid & 63;
    const int rg   = lane >> 4;              // group 0..3 (DPP row)
    const int kl   = lane & 15;              // k-lane 0..15
    const int rb   = blockIdx.x >> 6;        // row group 0..63
    const int sg   = blockIdx.x & 63;        // k segment 0..63
    const int r0   = rb * RPB;
    const int k00  = sg * KSEG;

    // ---- W loads FIRST (L2/L3-resident, cached on purpose: reused by all
    // row-group blocks sharing this k-segment) ----------------------------
    float4 wv0 = make_float4(0.f, 0.f, 0.f, 0.f);
    float4 wv1 = wv0, wv2 = wv0;
    if (tid < KSEG) {                        // threads 0..191, one k each
        const float* wr = W + (size_t)(k00 + tid) * 24;
        wv0 = *(const float4*)(wr + 0);      // cols 0..3
        wv1 = *(const float4*)(wr + 8);      // cols 8..11
        wv2 = *(const float4*)(wr + 16);     // cols 16..19
    }

    // ---- hoist ALL x loads: pure coalesced HBM miss stream, NT policy -----
    // f4 idx = kl + 16*jj -> each 16-lane group reads 256B contiguous.
    f4 xr[RPL][3];
#pragma unroll
    for (int r = 0; r < RPL; ++r) {
        const int row = r0 + w * 8 + rg * 2 + r;
        const float* xp = x + (size_t)row * DIM + k00 + kl * 4;
#pragma unroll
        for (int jj = 0; jj < 3; ++jj)
            xr[r][jj] = __builtin_nontemporal_load((const f4*)(xp + 64 * jj));
    }

    // ---- stage W -> LDS (waits only W's vmcnt slots, not the x misses) ----
    if (tid < KSEG) {
        wt[0 * KSEG + tid] = wv0.x;  wt[1 * KSEG + tid] = wv0.y;
        wt[2 * KSEG + tid] = wv0.z;  wt[3 * KSEG + tid] = wv0.w;
        wt[4 * KSEG + tid] = wv1.x;  wt[5 * KSEG + tid] = wv1.y;
        wt[6 * KSEG + tid] = wv1.z;  wt[7 * KSEG + tid] = wv1.w;
        wt[8 * KSEG + tid] = wv2.x;  wt[9 * KSEG + tid] = wv2.y;
        wt[10 * KSEG + tid] = wv2.z; wt[11 * KSEG + tid] = wv2.w;
    }
    __syncthreads();                         // the ONLY barrier

    float acc[RPL][NCOL];
#pragma unroll
    for (int r = 0; r < RPL; ++r)
#pragma unroll
        for (int c = 0; c < NCOL; ++c) acc[r][c] = 0.f;

    // ---- compute: 36 ds_read_b128 (2-way bank alias = free), 16 FMA each --
#pragma unroll
    for (int jj = 0; jj < 3; ++jj) {
        const int kq = kl * 4 + 64 * jj;
#pragma unroll
        for (int c = 0; c < NCOL; ++c) {
            const float4 q = *(const float4*)(wt + c * KSEG + kq);
#pragma unroll
            for (int r = 0; r < RPL; ++r)
                acc[r][c] += xr[r][jj].x * q.x + xr[r][jj].y * q.y +
                             xr[r][jj].z * q.z + xr[r][jj].w * q.w;
        }
    }

    // ---- 16-lane DPP rotate-add reduction (VALU only, no DS) --------------
#pragma unroll
    for (int r = 0; r < RPL; ++r)
#pragma unroll
        for (int c = 0; c < NCOL; ++c) {
            float s = acc[r][c];
            ROR16_ADD(s, 1);
            ROR16_ADD(s, 2);
            ROR16_ADD(s, 4);
            ROR16_ADD(s, 8);
            acc[r][c] = s;                   // all 16 lanes hold full sum
        }

    // ---- store: lane kl<12 owns column c=kl (static-index cndmask chain) --
    if (kl < NCOL) {
#pragma unroll
        for (int r = 0; r < RPL; ++r) {
            float v = acc[r][0];
#pragma unroll
            for (int c = 1; c < NCOL; ++c)
                if (kl == c) v = acc[r][c];
            const int row = r0 + w * 8 + rg * 2 + r;
            part[(size_t)sg * (ROWS * NCOL) + (size_t)row * NCOL + kl] = v;
        }
    }
}

// ---------------- Kernel 2: reduce split-K + constrain + match + fix -------
__global__ __launch_bounds__(64) void k_post(const float* __restrict__ part,
                                             const float* __restrict__ b_enc,
                                             float* __restrict__ out) {
    __shared__ float z[T_S * NCOL];
    __shared__ float zm[T_S * NCOL];
    __shared__ float zf[T_S * NCOL];
    __shared__ int   perm[T_S];
    const int b   = blockIdx.x;
    const int tid = threadIdx.x;

    // fused split-K reduce + bias + sigmoid constrain
#pragma unroll
    for (int ii = 0; ii < 6; ++ii) {
        const int i = tid + 64 * ii;              // t*12 + c for this batch row
        float s = 0.f;
#pragma unroll 16
        for (int sgi = 0; sgi < KSPL; ++sgi)
            s += part[(size_t)sgi * (ROWS * NCOL) + b * 384 + i];
        const int c  = i % 12;
        const int o  = c >> 2;
        const int cp = c & 3;
        s += b_enc[o * 8 + cp];
        const float sgm = 1.f / (1.f + expf(-s));
        float v;
        if (cp == 0)      v = sgm * 0.7f + 0.1f;
        else if (cp == 1) v = sgm * 0.5f + 0.75f;
        else              v = (2.f * sgm - 1.f) * 0.9f;
        z[i] = v;
    }
    __syncthreads();

    if (tid == 0) {
        float px0 = z[2],  py0 = z[3];
        float px1 = z[6],  py1 = z[7];
        float px2 = z[10], py2 = z[11];
        for (int t = 1; t < T_S; ++t) {
            const int base = t * 12;
            const float cx0 = z[base + 2],  cy0 = z[base + 3];
            const float cx1 = z[base + 6],  cy1 = z[base + 7];
            const float cx2 = z[base + 10], cy2 = z[base + 11];

            float dx, dy;
            dx = px0 - cx0; dy = py0 - cy0; const float e00 = dx * dx + dy * dy;
            dx = px0 - cx1; dy = py0 - cy1; const float e01 = dx * dx + dy * dy;
            dx = px0 - cx2; dy = py0 - cy2; const float e02 = dx * dx + dy * dy;
            dx = px1 - cx0; dy = py1 - cy0; const float e10 = dx * dx + dy * dy;
            dx = px1 - cx1; dy = py1 - cy1; const float e11 = dx * dx + dy * dy;
            dx = px1 - cx2; dy = py1 - cy2; const float e12 = dx * dx + dy * dy;
            dx = px2 - cx0; dy = py2 - cy0; const float e20 = dx * dx + dy * dy;
            dx = px2 - cx1; dy = py2 - cy1; const float e21 = dx * dx + dy * dy;
            dx = px2 - cx2; dy = py2 - cy2; const float e22 = dx * dx + dy * dy;

            auto amin3 = [](float a0, float a1, float a2) {
                int j = 0; float e = a0;
                if (a1 < e) { e = a1; j = 1; }
                if (a2 < e) { j = 2; }
                return j;
            };
            int i0 = amin3(e00, e01, e02);
            int i1 = amin3(e10, e11, e12);
            int i2 = amin3(e20, e21, e22);
            const bool ok = (i1 != i0) && (i2 != i1) && (i0 != i2);
            if (!ok) {
                float u0 = 0.f, u1 = 0.f, u2 = 0.f;
                i0 = amin3(e00, e01, e02);
                if (i0 == 0) u0 = 1.f; else if (i0 == 1) u1 = 1.f; else u2 = 1.f;
                i1 = amin3(e10 + u0 * 1e12f, e11 + u1 * 1e12f, e12 + u2 * 1e12f);
                if (i1 == 0) u0 = 1.f; else if (i1 == 1) u1 = 1.f; else u2 = 1.f;
                i2 = amin3(e20 + u0 * 1e12f, e21 + u1 * 1e12f, e22 + u2 * 1e12f);
            }
            perm[t] = i0 * 9 + i1 * 3 + i2;
            px0 = (i0 == 0) ? cx0 : (i0 == 1) ? cx1 : cx2;
            py0 = (i0 == 0) ? cy0 : (i0 == 1) ? cy1 : cy2;
            px1 = (i1 == 0) ? cx0 : (i1 == 1) ? cx1 : cx2;
            py1 = (i1 == 0) ? cy0 : (i1 == 1) ? cy1 : cy2;
            px2 = (i2 == 0) ? cx0 : (i2 == 1) ? cx1 : cx2;
            py2 = (i2 == 0) ? cy0 : (i2 == 1) ? cy1 : cy2;
        }
    }
    __syncthreads();

#pragma unroll
    for (int ii = 0; ii < 6; ++ii) {
        const int i  = tid + 64 * ii;
        const int t  = i / 12;
        const int j  = i - t * 12;
        const int k  = j >> 2;
        const int ch = j & 3;
        int p = k;
        if (t > 0) {
            const int code = perm[t];
            p = (k == 0) ? code / 9 : (k == 1) ? (code % 9) / 3 : code % 3;
        }
        zm[i] = z[t * 12 + p * 4 + ch];
    }
    __syncthreads();

#pragma unroll
    for (int ii = 0; ii < 6; ++ii) {
        const int i  = tid + 64 * ii;
        const int t  = i / 12;
        const int j  = i - t * 12;
        const int o  = j >> 2;
        const int cc = j & 1;
        const int mb = o * 4 + cc;
        const float pd = (t >= 1)  ? fabsf(zm[t * 12 + mb] - zm[(t - 1) * 12 + mb]) : 0.f;
        const float ad = (t <= 30) ? fabsf(zm[(t + 1) * 12 + mb] - zm[t * 12 + mb]) : 0.f;
        const bool  m  = (pd > 0.095f) && (ad > 0.095f);
        const float sm = (t >= 1 && t <= 30)
                             ? (zm[(t - 1) * 12 + j] + zm[(t + 1) * 12 + j]) * 0.5f
                             : 0.f;
        zf[i] = m ? sm : zm[t * 12 + j];
    }
    __syncthreads();

    for (int i = tid; i < 31 * 12; i += 64) {
        const int t  = i / 12;
        const int j  = i - t * 12;
        const int o  = j >> 2;
        const int c2 = j & 3;
        const int pb = o * 4 + 2 + (c2 & 1);
        float v;
        if (c2 < 2) v = zf[(t + 1) * 12 + pb] + 1.f;
        else        v = (zf[(t + 1) * 12 + pb] - zf[t * 12 + pb]) * 10.f;
        out[b * 372 + i] = v;
    }
}

extern "C" void kernel_launch(void* const* d_in, const int* in_sizes, int n_in,
                              void* d_out, int out_size, void* d_ws, size_t ws_size,
                              hipStream_t stream) {
    (void)in_sizes; (void)n_in; (void)out_size; (void)ws_size;
    const float* x     = (const float*)d_in[0];
    const float* W_enc = (const float*)d_in[1];
    const float* b_enc = (const float*)d_in[2];
    float* out  = (float*)d_out;

    float* part = (float*)d_ws;               // 64*24576 floats = 6.3 MB

    k_gemm3<<<(ROWS / RPB) * KSPL, 256, 0, stream>>>(x, W_enc, part);
    k_post <<<N_B, 64, 0, stream>>>(part, b_enc, out);
}

// Round 6
// 161.824 us; speedup vs baseline: 1.2565x; 1.0603x over previous
//
#include <hip/hip_runtime.h>

#define N_B    64
#define T_S    32
#define DIM    12288            // 3*64*64
#define ROWS   2048             // N_B*T_S
#define NCOL   12               // used GEMM columns (3 obj * 4)
#define KSPL   8                // split-K factor
#define KSEG   (DIM / KSPL)     // 1536
#define RPB    32               // rows per block (4 waves * 4 groups * 2 rows)
#define RPL    2                // rows per lane
#define NSUB   8                // sub-iterations (KSEG/4/16/3)

typedef float f4 __attribute__((ext_vector_type(4)));

// rotate-right within 16-lane DPP row, add into v (pure VALU, no DS pipe)
#define ROR16_ADD(v, n)                                                        \
    v += __int_as_float(__builtin_amdgcn_update_dpp(                           \
        0, __float_as_int(v), 0x120 | (n), 0xF, 0xF, true))

// ---------------- Kernel 1: resident-grid pipelined split-K GEMM -----------
// Grid: 512 blocks = 64 row-groups x 8 k-segments -> ENTIRE grid co-resident
// (2 blocks/CU, 72KB LDS each): zero dispatch ramp/tail. W panel staged to
// LDS once (ONE barrier); then 8 software-pipelined sub-iters walk K=1536
// with 12 NT x-loads continuously in flight per wave, x never in LDS, no
// further barriers. Each block streams 32 rows x 6KB (long DRAM strips).
// Reduction: 4 DPP rotate-adds within 16-lane groups (VALU only).
__global__ __launch_bounds__(256, 2) void k_gemm4(const float* __restrict__ x,
                                                  const float* __restrict__ W,
                                                  float* __restrict__ part) {
    __shared__ float wt[NCOL * KSEG];        // [c][k], 73728 B
    const int tid  = threadIdx.x;
    const int w    = tid >> 6;
    const int lane = tid & 63;
    const int rg   = lane >> 4;              // group 0..3 (DPP row)
    const int kl   = lane & 15;              // k-lane 0..15
    const int rb   = blockIdx.x >> 3;        // row group 0..63
    const int sg   = blockIdx.x & 7;         // k segment 0..7
    const int r0   = rb * RPB;
    const int k00  = sg * KSEG;

    // ---- stage W segment -> LDS (once per block; L2/L3-resident source) ---
#pragma unroll
    for (int i = 0; i < 6; ++i) {
        const int k = tid + 256 * i;         // 0..1535
        const float* wr = W + (size_t)(k00 + k) * 24;
        const float4 a = *(const float4*)(wr + 0);    // cols 0..3
        const float4 b = *(const float4*)(wr + 8);    // cols 8..11
        const float4 c = *(const float4*)(wr + 16);   // cols 16..19
        wt[0 * KSEG + k]  = a.x;  wt[1 * KSEG + k]  = a.y;
        wt[2 * KSEG + k]  = a.z;  wt[3 * KSEG + k]  = a.w;
        wt[4 * KSEG + k]  = b.x;  wt[5 * KSEG + k]  = b.y;
        wt[6 * KSEG + k]  = b.z;  wt[7 * KSEG + k]  = b.w;
        wt[8 * KSEG + k]  = c.x;  wt[9 * KSEG + k]  = c.y;
        wt[10 * KSEG + k] = c.z;  wt[11 * KSEG + k] = c.w;
    }
    __syncthreads();                         // the ONLY barrier

    const float* xp0 = x + (size_t)(r0 + w * 8 + rg * 2 + 0) * DIM + k00 + kl * 4;
    const float* xp1 = x + (size_t)(r0 + w * 8 + rg * 2 + 1) * DIM + k00 + kl * 4;

    float acc[RPL][NCOL];
#pragma unroll
    for (int r = 0; r < RPL; ++r)
#pragma unroll
        for (int c = 0; c < NCOL; ++c) acc[r][c] = 0.f;

    // ---- prologue: sub-iter 0 loads (NT: zero-reuse, don't pollute L3) ----
    f4 xb[2][RPL][3];
#pragma unroll
    for (int t = 0; t < 3; ++t) {
        xb[0][0][t] = __builtin_nontemporal_load((const f4*)(xp0 + 64 * t));
        xb[0][1][t] = __builtin_nontemporal_load((const f4*)(xp1 + 64 * t));
    }

    // ---- pipelined K-walk: 8 sub-iters, 12 loads in flight, no barriers ---
#pragma unroll
    for (int j = 0; j < NSUB; ++j) {
        const int cur = j & 1, nxt = cur ^ 1;
        if (j + 1 < NSUB) {
            const int off = 192 * (j + 1);
#pragma unroll
            for (int t = 0; t < 3; ++t) {
                xb[nxt][0][t] =
                    __builtin_nontemporal_load((const f4*)(xp0 + off + 64 * t));
                xb[nxt][1][t] =
                    __builtin_nontemporal_load((const f4*)(xp1 + off + 64 * t));
            }
        }
#pragma unroll
        for (int t = 0; t < 3; ++t) {
            const int kq = kl * 4 + 192 * j + 64 * t;  // float offset in wt
#pragma unroll
            for (int c = 0; c < NCOL; ++c) {
                const float4 q = *(const float4*)(wt + c * KSEG + kq);
#pragma unroll
                for (int r = 0; r < RPL; ++r)
                    acc[r][c] += xb[cur][r][t].x * q.x + xb[cur][r][t].y * q.y +
                                 xb[cur][r][t].z * q.z + xb[cur][r][t].w * q.w;
            }
        }
    }

    // ---- 16-lane DPP rotate-add reduction (VALU only, no DS) --------------
#pragma unroll
    for (int r = 0; r < RPL; ++r)
#pragma unroll
        for (int c = 0; c < NCOL; ++c) {
            float s = acc[r][c];
            ROR16_ADD(s, 1);
            ROR16_ADD(s, 2);
            ROR16_ADD(s, 4);
            ROR16_ADD(s, 8);
            acc[r][c] = s;                   // all 16 lanes hold full sum
        }

    // ---- store: lane kl<12 owns column c=kl (static-index select chain) ---
    if (kl < NCOL) {
#pragma unroll
        for (int r = 0; r < RPL; ++r) {
            float v = acc[r][0];
#pragma unroll
            for (int c = 1; c < NCOL; ++c)
                if (kl == c) v = acc[r][c];
            const int row = r0 + w * 8 + rg * 2 + r;
            part[(size_t)sg * (ROWS * NCOL) + (size_t)row * NCOL + kl] = v;
        }
    }
}

// ---------------- Kernel 2: reduce split-K + constrain + match + fix -------
__global__ __launch_bounds__(64) void k_post(const float* __restrict__ part,
                                             const float* __restrict__ b_enc,
                                             float* __restrict__ out) {
    __shared__ float z[T_S * NCOL];
    __shared__ float zm[T_S * NCOL];
    __shared__ float zf[T_S * NCOL];
    __shared__ int   perm[T_S];
    const int b   = blockIdx.x;
    const int tid = threadIdx.x;

    // fused split-K reduce + bias + sigmoid constrain
#pragma unroll
    for (int ii = 0; ii < 6; ++ii) {
        const int i = tid + 64 * ii;              // t*12 + c for this batch row
        float s = 0.f;
#pragma unroll
        for (int sgi = 0; sgi < KSPL; ++sgi)
            s += part[(size_t)sgi * (ROWS * NCOL) + b * 384 + i];
        const int c  = i % 12;
        const int o  = c >> 2;
        const int cp = c & 3;
        s += b_enc[o * 8 + cp];
        const float sgm = 1.f / (1.f + expf(-s));
        float v;
        if (cp == 0)      v = sgm * 0.7f + 0.1f;
        else if (cp == 1) v = sgm * 0.5f + 0.75f;
        else              v = (2.f * sgm - 1.f) * 0.9f;
        z[i] = v;
    }
    __syncthreads();

    if (tid == 0) {
        float px0 = z[2],  py0 = z[3];
        float px1 = z[6],  py1 = z[7];
        float px2 = z[10], py2 = z[11];
        for (int t = 1; t < T_S; ++t) {
            const int base = t * 12;
            const float cx0 = z[base + 2],  cy0 = z[base + 3];
            const float cx1 = z[base + 6],  cy1 = z[base + 7];
            const float cx2 = z[base + 10], cy2 = z[base + 11];

            float dx, dy;
            dx = px0 - cx0; dy = py0 - cy0; const float e00 = dx * dx + dy * dy;
            dx = px0 - cx1; dy = py0 - cy1; const float e01 = dx * dx + dy * dy;
            dx = px0 - cx2; dy = py0 - cy2; const float e02 = dx * dx + dy * dy;
            dx = px1 - cx0; dy = py1 - cy0; const float e10 = dx * dx + dy * dy;
            dx = px1 - cx1; dy = py1 - cy1; const float e11 = dx * dx + dy * dy;
            dx = px1 - cx2; dy = py1 - cy2; const float e12 = dx * dx + dy * dy;
            dx = px2 - cx0; dy = py2 - cy0; const float e20 = dx * dx + dy * dy;
            dx = px2 - cx1; dy = py2 - cy1; const float e21 = dx * dx + dy * dy;
            dx = px2 - cx2; dy = py2 - cy2; const float e22 = dx * dx + dy * dy;

            auto amin3 = [](float a0, float a1, float a2) {
                int j = 0; float e = a0;
                if (a1 < e) { e = a1; j = 1; }
                if (a2 < e) { j = 2; }
                return j;
            };
            int i0 = amin3(e00, e01, e02);
            int i1 = amin3(e10, e11, e12);
            int i2 = amin3(e20, e21, e22);
            const bool ok = (i1 != i0) && (i2 != i1) && (i0 != i2);
            if (!ok) {
                float u0 = 0.f, u1 = 0.f, u2 = 0.f;
                i0 = amin3(e00, e01, e02);
                if (i0 == 0) u0 = 1.f; else if (i0 == 1) u1 = 1.f; else u2 = 1.f;
                i1 = amin3(e10 + u0 * 1e12f, e11 + u1 * 1e12f, e12 + u2 * 1e12f);
                if (i1 == 0) u0 = 1.f; else if (i1 == 1) u1 = 1.f; else u2 = 1.f;
                i2 = amin3(e20 + u0 * 1e12f, e21 + u1 * 1e12f, e22 + u2 * 1e12f);
            }
            perm[t] = i0 * 9 + i1 * 3 + i2;
            px0 = (i0 == 0) ? cx0 : (i0 == 1) ? cx1 : cx2;
            py0 = (i0 == 0) ? cy0 : (i0 == 1) ? cy1 : cy2;
            px1 = (i1 == 0) ? cx0 : (i1 == 1) ? cx1 : cx2;
            py1 = (i1 == 0) ? cy0 : (i1 == 1) ? cy1 : cy2;
            px2 = (i2 == 0) ? cx0 : (i2 == 1) ? cx1 : cx2;
            py2 = (i2 == 0) ? cy0 : (i2 == 1) ? cy1 : cy2;
        }
    }
    __syncthreads();

#pragma unroll
    for (int ii = 0; ii < 6; ++ii) {
        const int i  = tid + 64 * ii;
        const int t  = i / 12;
        const int j  = i - t * 12;
        const int k  = j >> 2;
        const int ch = j & 3;
        int p = k;
        if (t > 0) {
            const int code = perm[t];
            p = (k == 0) ? code / 9 : (k == 1) ? (code % 9) / 3 : code % 3;
        }
        zm[i] = z[t * 12 + p * 4 + ch];
    }
    __syncthreads();

#pragma unroll
    for (int ii = 0; ii < 6; ++ii) {
        const int i  = tid + 64 * ii;
        const int t  = i / 12;
        const int j  = i - t * 12;
        const int o  = j >> 2;
        const int cc = j & 1;
        const int mb = o * 4 + cc;
        const float pd = (t >= 1)  ? fabsf(zm[t * 12 + mb] - zm[(t - 1) * 12 + mb]) : 0.f;
        const float ad = (t <= 30) ? fabsf(zm[(t + 1) * 12 + mb] - zm[t * 12 + mb]) : 0.f;
        const bool  m  = (pd > 0.095f) && (ad > 0.095f);
        const float sm = (t >= 1 && t <= 30)
                             ? (zm[(t - 1) * 12 + j] + zm[(t + 1) * 12 + j]) * 0.5f
                             : 0.f;
        zf[i] = m ? sm : zm[t * 12 + j];
    }
    __syncthreads();

    for (int i = tid; i < 31 * 12; i += 64) {
        const int t  = i / 12;
        const int j  = i - t * 12;
        const int o  = j >> 2;
        const int c2 = j & 3;
        const int pb = o * 4 + 2 + (c2 & 1);
        float v;
        if (c2 < 2) v = zf[(t + 1) * 12 + pb] + 1.f;
        else        v = (zf[(t + 1) * 12 + pb] - zf[t * 12 + pb]) * 10.f;
        out[b * 372 + i] = v;
    }
}

extern "C" void kernel_launch(void* const* d_in, const int* in_sizes, int n_in,
                              void* d_out, int out_size, void* d_ws, size_t ws_size,
                              hipStream_t stream) {
    (void)in_sizes; (void)n_in; (void)out_size; (void)ws_size;
    const float* x     = (const float*)d_in[0];
    const float* W_enc = (const float*)d_in[1];
    const float* b_enc = (const float*)d_in[2];
    float* out  = (float*)d_out;

    float* part = (float*)d_ws;               // 8*24576 floats = 786 KB

    k_gemm4<<<(ROWS / RPB) * KSPL, 256, 0, stream>>>(x, W_enc, part);
    k_post <<<N_B, 64, 0, stream>>>(part, b_enc, out);
}